// Round 10
// baseline (285.090 us; speedup 1.0000x reference)
//
#include <hip/hip_runtime.h>

// RBFolution: out[b,y,x,f] = exp(-beta[f] * (||patch||^2 - 2 patch.ccs[:,f] + ||ccs[:,f]||^2))
// x: [32,112,112,32] f32, ccs: [288,128] f32, beta: [128] f32, out: [32,110,110,128] f32
//
// bf16 MFMA implicit GEMM; p_sq/c_sq fp32-exact (only cross term bf16, err ~1e-5).
// R14: COLUMN SPLIT. Ledger: nt+full-line stores proven (R9 best 262.3; cached full-line
// R13 -17us worse; nt partial R7 worse); ORPB parabola {1:127, 2:113, 4:118, 8p:137};
// R12's ORPB=1 loss was VERTICAL refetch (3x), not small blocks per se. Decouple:
// block = 2 rows x 56 px (stage 4 rows x 58 px). Blocks 1760->3520 at ~R9 stage-work
// per output (horizontal refetch 58/56 = 1.036x only). LDS 16.5KB, acc 32 regs ->
// residency capped by HW 8 blocks/CU (was 2.7 by LDS). MFMA pad 64/56 free (8.7% util).

typedef __attribute__((ext_vector_type(8))) short bf16x8;
typedef __attribute__((ext_vector_type(4))) float f32x4;

#define HH 112
#define WW 112
#define CC 32
#define HO 110
#define WO 110
#define NF 128
#define KD 288
#define RPXC 58        // staged pixels per row (56 outputs + 2 border)
#define XP 32          // bf16 elems per pixel (64 B)
#define CSPC 60        // colsum row pitch
#define ORPB 2         // output rows per block
#define SROWS 4        // staged input rows per block
#define OCOL 56        // output columns per block

__device__ __forceinline__ unsigned short f32_to_bf16(float f) {
    unsigned u = __float_as_uint(f);
    unsigned r = u + 0x7FFFu + ((u >> 16) & 1u);   // round-to-nearest-even
    return (unsigned short)(r >> 16);
}

// --- Prologue: ccs [288][128] f32 -> ccs_t [128][288] bf16 (all blocks);
//     block 0 threads 0..127 also compute c_sq[f] = sum_d ccs[d][f]^2.
__global__ __launch_bounds__(256) void rbf_prologue(const float* __restrict__ ccs,
                                                    unsigned short* __restrict__ ccs_t,
                                                    float* __restrict__ c_sq) {
    int idx = blockIdx.x * 256 + threadIdx.x;     // 0..36863, coalesced read
    int d = idx >> 7;
    int f = idx & 127;
    ccs_t[f * KD + d] = f32_to_bf16(ccs[idx]);
    if (blockIdx.x == 0 && threadIdx.x < 128) {
        const int fc = threadIdx.x;
        float s = 0.f;
        #pragma unroll 8
        for (int dd = 0; dd < KD; ++dd) {
            float v = ccs[dd * NF + fc];
            s += v * v;
        }
        c_sq[fc] = s;
    }
}

// --- Main: one block per (2-row strip, 56-px column half, b).
__global__ __launch_bounds__(256) void rbf_main(const float* __restrict__ x,
                                                const unsigned short* __restrict__ ccs_t,
                                                const float* __restrict__ c_sq,
                                                const float* __restrict__ beta,
                                                float* __restrict__ out) {
    __shared__ unsigned short xs[(SROWS * RPXC + 8) * XP];  // 15360 B (pad: masked-lane reads reach (3*58+65))
    __shared__ float colsum[SROWS * CSPC + 8];              // 992 B  (pad: c up to 63 in p_sq phase)
    __shared__ float p_sq[ORPB * 64];                       // 512 B  -> 16.5 KB total

    const int t = threadIdx.x;
    const int strip = blockIdx.x >> 1;
    const int cb    = blockIdx.x & 1;
    const int y0 = strip * ORPB;       // 0,2,...,108
    const int x0 = cb * OCOL;          // 0 or 56
    const int b  = blockIdx.y;         // 0..31

    const int lane  = t & 63;
    const int wave  = t >> 6;            // 4 waves x 32 filters
    const int laneM = lane & 15;
    const int quad  = lane >> 4;
    const int pl    = laneM & 1;         // pair parity for full-line stores

    // Stage x[y0..y0+3][x0..x0+57][0..31] -> LDS bf16; colsum from fp32 (exact p_sq).
    // 4*58*8 = 1856 float4 units = 7.25*256 (tail: wave 0 only -- wave-uniform guard).
    // Global col clamped to 111 (cb=1 cols 112,113 -> dup of 111; reads for valid
    // outputs only reach staged local px 55, so clamp garbage feeds masked lanes only).
    #pragma unroll
    for (int p = 0; p < 8; ++p) {
        int idx = t + p * 256;
        if (idx < SROWS * RPXC * 8) {
            int q = idx & 7;              // channel quarter (4 floats)
            int ic = idx >> 3;            // 0..231 = i*58 + col
            int col = ic % RPXC;
            int i = ic / RPXC;            // 0..3
            int cg = x0 + col; if (cg > WW - 1) cg = WW - 1;
            const float4 v = *(const float4*)(x + ((size_t)(b * HH + y0 + i) * WW + cg) * CC + q * 4);
            unsigned short h0 = f32_to_bf16(v.x), h1 = f32_to_bf16(v.y);
            unsigned short h2 = f32_to_bf16(v.z), h3 = f32_to_bf16(v.w);
            uint2 pk;
            pk.x = (unsigned)h0 | ((unsigned)h1 << 16);
            pk.y = (unsigned)h2 | ((unsigned)h3 << 16);
            *(uint2*)(&xs[(i * RPXC + col) * XP + q * 4]) = pk;   // 8B, contiguous per wave
            float part = v.x * v.x + v.y * v.y + v.z * v.z + v.w * v.w;
            part += __shfl_xor(part, 1);
            part += __shfl_xor(part, 2);
            part += __shfl_xor(part, 4);
            if (q == 0) colsum[i * CSPC + col] = part;
        }
    }
    __syncthreads();

    if (t < ORPB * 64) {   // 128 threads; c >= 56 computes garbage (masked px only)
        int r = t >> 6;
        int c = t & 63;
        float s = 0.f;
        #pragma unroll
        for (int i = 0; i < 3; ++i)
            #pragma unroll
            for (int j = 0; j < 3; ++j)
                s += colsum[(r + i) * CSPC + c + j];
        p_sq[t] = s;
    }
    __syncthreads();

    // A = ccs (M = filters): lane's filter-in-tile = laneM
    const unsigned short* ap0 = ccs_t + (size_t)(wave * 32 + laneM) * KD + quad * 8;
    const unsigned short* ap1 = ap0 + 16 * KD;

    // per-lane 4 consecutive filters (rows of D): f = wave*32 + ft*16 + quad*4 + e
    const int fb = wave * 32 + quad * 4;
    const float4 cs0 = *(const float4*)(c_sq + fb);
    const float4 cs1 = *(const float4*)(c_sq + fb + 16);
    const float4 bt0 = *(const float4*)(beta + fb);
    const float4 bt1 = *(const float4*)(beta + fb + 16);

    for (int r = 0; r < ORPB; ++r) {
        f32x4 acc[4][2];
        #pragma unroll
        for (int mi = 0; mi < 4; ++mi) {
            acc[mi][0] = (f32x4){0.f, 0.f, 0.f, 0.f};
            acc[mi][1] = (f32x4){0.f, 0.f, 0.f, 0.f};
        }

        #pragma unroll
        for (int kb = 0; kb < 9; ++kb) {     // one k-block per tap (ki,kj), K=32 channels
            const int ki = kb / 3, kj = kb % 3;
            bf16x8 a0 = *(const bf16x8*)(ap0 + kb * 32);
            bf16x8 a1 = *(const bf16x8*)(ap1 + kb * 32);
            #pragma unroll
            for (int mi = 0; mi < 4; ++mi) {
                // B[k = quad*8+j][n = laneM]: local px = mi*16+laneM+kj, staged row r+ki.
                // mi=3, laneM>=8: reads past row pitch into pad -- feeds masked outputs only.
                const bf16x8 bf = *(const bf16x8*)(&xs[((r + ki) * RPXC + mi * 16 + laneM + kj) * XP + quad * 8]);
                acc[mi][0] = __builtin_amdgcn_mfma_f32_16x16x32_bf16(a0, bf, acc[mi][0], 0, 0, 0);
                acc[mi][1] = __builtin_amdgcn_mfma_f32_16x16x32_bf16(a1, bf, acc[mi][1], 0, 0, 0);
            }
        }

        // Epilogue: lane holds local px = mi*16+laneM, filters {fb..fb+3, fb+16..fb+19}.
        // Lane-pair swap (xor 1): instr 1 writes EVEN pixels' full 128B lines, instr 2 ODD.
        // nt stores (R9/R13 A/B: nt+full-line is the proven combination).
        float* orow = out + (size_t)((b * HO + y0 + r) * WO) * NF;
        #pragma unroll
        for (int mi = 0; mi < 4; ++mi) {
            const int px = mi * 16 + laneM;            // local
            const float ps = p_sq[r * 64 + px];
            f32x4 o0, o1;
            o0[0] = __expf(-bt0.x * (ps - 2.f * acc[mi][0][0] + cs0.x));
            o0[1] = __expf(-bt0.y * (ps - 2.f * acc[mi][0][1] + cs0.y));
            o0[2] = __expf(-bt0.z * (ps - 2.f * acc[mi][0][2] + cs0.z));
            o0[3] = __expf(-bt0.w * (ps - 2.f * acc[mi][0][3] + cs0.w));
            o1[0] = __expf(-bt1.x * (ps - 2.f * acc[mi][1][0] + cs1.x));
            o1[1] = __expf(-bt1.y * (ps - 2.f * acc[mi][1][1] + cs1.y));
            o1[2] = __expf(-bt1.z * (ps - 2.f * acc[mi][1][2] + cs1.z));
            o1[3] = __expf(-bt1.w * (ps - 2.f * acc[mi][1][3] + cs1.w));

            // even lane sends its ft1 half, odd lane sends its ft0 half; partner receives.
            f32x4 sendv = pl ? o0 : o1;
            f32x4 recv;
            recv[0] = __shfl_xor(sendv[0], 1);
            recv[1] = __shfl_xor(sendv[1], 1);
            recv[2] = __shfl_xor(sendv[2], 1);
            recv[3] = __shfl_xor(sendv[3], 1);
            const f32x4 v1 = pl ? recv : o0;   // even-pixel full line
            const f32x4 v2 = pl ? o1 : recv;   // odd-pixel full line

            const int pxe = mi * 16 + (laneM & ~1);    // local even pixel of the pair
            const int gpxe = x0 + pxe;                 // global pixel
            float* op1 = orow + (size_t)gpxe * NF + fb + pl * 16;
            if (pxe < OCOL && gpxe < WO)
                __builtin_nontemporal_store(v1, (f32x4*)op1);
            if (pxe < OCOL && gpxe + 1 < WO)
                __builtin_nontemporal_store(v2, (f32x4*)(op1 + NF));
        }
    }
}

extern "C" void kernel_launch(void* const* d_in, const int* in_sizes, int n_in,
                              void* d_out, int out_size, void* d_ws, size_t ws_size,
                              hipStream_t stream) {
    const float* x    = (const float*)d_in[0];
    const float* ccs  = (const float*)d_in[1];
    const float* beta = (const float*)d_in[2];
    float* out = (float*)d_out;

    unsigned short* ccs_t = (unsigned short*)d_ws;                              // 128*288 bf16
    float* c_sq = (float*)((char*)d_ws + 128 * KD * sizeof(unsigned short));    // 128 f32

    rbf_prologue<<<144, 256, 0, stream>>>(ccs, ccs_t, c_sq);
    rbf_main<<<dim3(110, 32), 256, 0, stream>>>(x, ccs_t, c_sq, beta, out);   // 55 strips x 2 cols
}

// Round 11
// 275.422 us; speedup vs baseline: 1.0351x; 1.0351x over previous
//
#include <hip/hip_runtime.h>

// RBFolution: out[b,y,x,f] = exp(-beta[f] * (||patch||^2 - 2 patch.ccs[:,f] + ||ccs[:,f]||^2))
// x: [32,112,112,32] f32, ccs: [288,128] f32, beta: [128] f32, out: [32,110,110,128] f32
//
// bf16 MFMA implicit GEMM; p_sq/c_sq fp32-exact (only cross term bf16, err ~1e-5).
// R15: 8 WAVES/BLOCK (512 thr), same block geometry as R9 (best, 262.3us).
// Ledger: nt+full-line stores proven (R9 vs R7/R13); ORPB parabola {1:127,2:113,4:118};
// column-split worse (R14); grid-axis exhausted. Model: R11's clean measurement implies
// ~8k cyc per output row per block = ~5x pipe-sum -> per-wave SERIAL latency chains
// (63 ds_read->MFMA + 56 exp + store drain) with only ~10 waves/CU to interleave.
// Fix: wave = (filter-group w&3) x (mi-parity w>>2). Per-wave chain HALVES
// (32 ds_read, 63 MFMA, 28 exp/row); waves/CU doubles at IDENTICAL staging cost/LDS
// (the decoupling R5/R8/R12/R14 lacked). mi-parity via template (no runtime acc idx).

typedef __attribute__((ext_vector_type(8))) short bf16x8;
typedef __attribute__((ext_vector_type(4))) float f32x4;

#define HH 112
#define WW 112
#define CC 32
#define HO 110
#define WO 110
#define NF 128
#define KD 288
#define RPX 114        // pixels per staged row (reads reach px 113)
#define XP 32          // bf16 elems per pixel (64 B)
#define CSP 116        // colsum row pitch (reads reach col 113)
#define ORPB 2         // output rows per block
#define SROWS 4        // staged input rows per block

__device__ __forceinline__ unsigned short f32_to_bf16(float f) {
    unsigned u = __float_as_uint(f);
    unsigned r = u + 0x7FFFu + ((u >> 16) & 1u);   // round-to-nearest-even
    return (unsigned short)(r >> 16);
}

// --- Prologue: ccs [288][128] f32 -> ccs_t [128][288] bf16 (all blocks);
//     block 0 threads 0..127 also compute c_sq[f] = sum_d ccs[d][f]^2.
__global__ __launch_bounds__(256) void rbf_prologue(const float* __restrict__ ccs,
                                                    unsigned short* __restrict__ ccs_t,
                                                    float* __restrict__ c_sq) {
    int idx = blockIdx.x * 256 + threadIdx.x;     // 0..36863, coalesced read
    int d = idx >> 7;
    int f = idx & 127;
    ccs_t[f * KD + d] = f32_to_bf16(ccs[idx]);
    if (blockIdx.x == 0 && threadIdx.x < 128) {
        const int fc = threadIdx.x;
        float s = 0.f;
        #pragma unroll 8
        for (int dd = 0; dd < KD; ++dd) {
            float v = ccs[dd * NF + fc];
            s += v * v;
        }
        c_sq[fc] = s;
    }
}

// Compute + epilogue for this wave's mi set: mi = 2*j + MIP, j < NMI.
template<int NMI, int MIP>
__device__ __forceinline__ void compute_rows(const unsigned short* __restrict__ xs,
                                             const float* __restrict__ p_sq,
                                             const unsigned short* __restrict__ ap0,
                                             const unsigned short* __restrict__ ap1,
                                             int laneM, int quad, int pl, int fb,
                                             float4 cs0, float4 cs1, float4 bt0, float4 bt1,
                                             float* __restrict__ out, int b, int y0) {
    for (int r = 0; r < ORPB; ++r) {
        f32x4 acc[NMI][2];
        #pragma unroll
        for (int j = 0; j < NMI; ++j) {
            acc[j][0] = (f32x4){0.f, 0.f, 0.f, 0.f};
            acc[j][1] = (f32x4){0.f, 0.f, 0.f, 0.f};
        }

        #pragma unroll
        for (int kb = 0; kb < 9; ++kb) {     // one k-block per tap (ki,kj), K=32 channels
            const int ki = kb / 3, kj = kb % 3;
            bf16x8 a0 = *(const bf16x8*)(ap0 + kb * 32);
            bf16x8 a1 = *(const bf16x8*)(ap1 + kb * 32);
            #pragma unroll
            for (int j = 0; j < NMI; ++j) {
                const int mi = 2 * j + MIP;
                // B[k = quad*8+jj][n = laneM]: pixel px = mi*16+laneM+kj, staged row r+ki
                const bf16x8 bf = *(const bf16x8*)(&xs[((r + ki) * RPX + mi * 16 + laneM + kj) * XP + quad * 8]);
                acc[j][0] = __builtin_amdgcn_mfma_f32_16x16x32_bf16(a0, bf, acc[j][0], 0, 0, 0);
                acc[j][1] = __builtin_amdgcn_mfma_f32_16x16x32_bf16(a1, bf, acc[j][1], 0, 0, 0);
            }
        }

        // Epilogue: lane holds pixel px = mi*16+laneM, filters {fb..fb+3, fb+16..fb+19}.
        // Lane-pair swap (xor 1): instr 1 writes EVEN pixels' full 128B lines, instr 2 ODD.
        // nt stores (proven combo, R9 vs R7/R13).
        float* orow = out + (size_t)((b * HO + y0 + r) * WO) * NF;
        #pragma unroll
        for (int j = 0; j < NMI; ++j) {
            const int mi = 2 * j + MIP;
            const int px = mi * 16 + laneM;
            const float ps = p_sq[r * 112 + px];
            f32x4 o0, o1;
            o0[0] = __expf(-bt0.x * (ps - 2.f * acc[j][0][0] + cs0.x));
            o0[1] = __expf(-bt0.y * (ps - 2.f * acc[j][0][1] + cs0.y));
            o0[2] = __expf(-bt0.z * (ps - 2.f * acc[j][0][2] + cs0.z));
            o0[3] = __expf(-bt0.w * (ps - 2.f * acc[j][0][3] + cs0.w));
            o1[0] = __expf(-bt1.x * (ps - 2.f * acc[j][1][0] + cs1.x));
            o1[1] = __expf(-bt1.y * (ps - 2.f * acc[j][1][1] + cs1.y));
            o1[2] = __expf(-bt1.z * (ps - 2.f * acc[j][1][2] + cs1.z));
            o1[3] = __expf(-bt1.w * (ps - 2.f * acc[j][1][3] + cs1.w));

            // even lane sends its ft1 half, odd lane sends its ft0 half; partner receives.
            f32x4 sendv = pl ? o0 : o1;
            f32x4 recv;
            recv[0] = __shfl_xor(sendv[0], 1);
            recv[1] = __shfl_xor(sendv[1], 1);
            recv[2] = __shfl_xor(sendv[2], 1);
            recv[3] = __shfl_xor(sendv[3], 1);
            const f32x4 v1 = pl ? recv : o0;   // even-pixel full line
            const f32x4 v2 = pl ? o1 : recv;   // odd-pixel full line

            const int pxe = mi * 16 + (laneM & ~1);   // even pixel of the pair
            float* op1 = orow + (size_t)pxe * NF + fb + pl * 16;
            if (pxe < WO)
                __builtin_nontemporal_store(v1, (f32x4*)op1);
            if (pxe + 1 < WO)
                __builtin_nontemporal_store(v2, (f32x4*)(op1 + NF));
        }
    }
}

// --- Main: one block per (2-row strip, b). 8 waves: 4 filter-groups x 2 mi-parities.
__global__ __launch_bounds__(512) void rbf_main(const float* __restrict__ x,
                                                const unsigned short* __restrict__ ccs_t,
                                                const float* __restrict__ c_sq,
                                                const float* __restrict__ beta,
                                                float* __restrict__ out) {
    __shared__ unsigned short xs[SROWS * RPX * XP];   // 29184 B
    __shared__ float colsum[SROWS * CSP];             // 1856 B
    __shared__ float p_sq[ORPB * 112];                // 896 B -> 31.2 KB total

    const int t = threadIdx.x;
    const int y0 = blockIdx.x * ORPB;  // 0,2,...,108 (55 strips exactly, no tail)
    const int b = blockIdx.y;          // 0..31

    const int lane  = t & 63;
    const int wave  = t >> 6;            // 0..7
    const int wgrp  = wave & 3;          // filter group (32 filters)
    const int mipar = wave >> 2;         // 0: mi even (4 tiles), 1: mi odd (3 tiles)
    const int laneM = lane & 15;
    const int quad  = lane >> 4;
    const int pl    = laneM & 1;         // pair parity for full-line stores

    // Stage x[y0..y0+3][0..111][0..31] -> LDS bf16; colsum from fp32 (exact p_sq).
    // 3584 float4 units = 7 * 512 exactly (no tail). y0+3 <= 111 always (no clamp).
    #pragma unroll
    for (int p = 0; p < 7; ++p) {
        int idx = t + p * 512;
        int q = idx & 7;              // channel quarter (4 floats); == lane&7
        int ic = idx >> 3;            // 0..447 = i*112 + col
        int col = ic % 112;
        int i = ic / 112;
        const float4 v = *(const float4*)(x + ((size_t)(b * HH + y0 + i) * WW + col) * CC + q * 4);
        unsigned short h0 = f32_to_bf16(v.x), h1 = f32_to_bf16(v.y);
        unsigned short h2 = f32_to_bf16(v.z), h3 = f32_to_bf16(v.w);
        uint2 pk;
        pk.x = (unsigned)h0 | ((unsigned)h1 << 16);
        pk.y = (unsigned)h2 | ((unsigned)h3 << 16);
        *(uint2*)(&xs[(i * RPX + col) * XP + q * 4]) = pk;   // 8B, contiguous per wave
        float part = v.x * v.x + v.y * v.y + v.z * v.z + v.w * v.w;
        part += __shfl_xor(part, 1);
        part += __shfl_xor(part, 2);
        part += __shfl_xor(part, 4);
        if (q == 0) colsum[i * CSP + col] = part;
    }
    __syncthreads();

    if (t < ORPB * 112) {   // 224 threads
        int r = t / 112;
        int c = t - r * 112;
        float s = 0.f;
        #pragma unroll
        for (int i = 0; i < 3; ++i)
            #pragma unroll
            for (int j = 0; j < 3; ++j)
                s += colsum[(r + i) * CSP + c + j];   // c>=110: in-pitch garbage -> masked px only
        p_sq[t] = s;
    }
    __syncthreads();

    // A = ccs (M = filters): lane's filter-in-tile = laneM
    const unsigned short* ap0 = ccs_t + (size_t)(wgrp * 32 + laneM) * KD + quad * 8;
    const unsigned short* ap1 = ap0 + 16 * KD;

    // per-lane 4 consecutive filters (rows of D): f = wgrp*32 + ft*16 + quad*4 + e
    const int fb = wgrp * 32 + quad * 4;
    const float4 cs0 = *(const float4*)(c_sq + fb);
    const float4 cs1 = *(const float4*)(c_sq + fb + 16);
    const float4 bt0 = *(const float4*)(beta + fb);
    const float4 bt1 = *(const float4*)(beta + fb + 16);

    if (mipar == 0)
        compute_rows<4, 0>(xs, p_sq, ap0, ap1, laneM, quad, pl, fb, cs0, cs1, bt0, bt1, out, b, y0);
    else
        compute_rows<3, 1>(xs, p_sq, ap0, ap1, laneM, quad, pl, fb, cs0, cs1, bt0, bt1, out, b, y0);
}

extern "C" void kernel_launch(void* const* d_in, const int* in_sizes, int n_in,
                              void* d_out, int out_size, void* d_ws, size_t ws_size,
                              hipStream_t stream) {
    const float* x    = (const float*)d_in[0];
    const float* ccs  = (const float*)d_in[1];
    const float* beta = (const float*)d_in[2];
    float* out = (float*)d_out;

    unsigned short* ccs_t = (unsigned short*)d_ws;                              // 128*288 bf16
    float* c_sq = (float*)((char*)d_ws + 128 * KD * sizeof(unsigned short));    // 128 f32

    rbf_prologue<<<144, 256, 0, stream>>>(ccs, ccs_t, c_sq);
    rbf_main<<<dim3(55, 32), 512, 0, stream>>>(x, ccs_t, c_sq, beta, out);
}